// Round 6
// baseline (417.400 us; speedup 1.0000x reference)
//
#include <hip/hip_runtime.h>
#include <hip/hip_bf16.h>
#include <stdint.h>

#define D_MODEL 1024
#define NH 16
#define HD 64
#define LSEQ 2048
#define BATCH 4
#define NROWS (BATCH * LSEQ) /* 8192 */
#define SCALE_L2E 0.18033688011112042f /* 0.125 * log2(e) */

typedef __attribute__((ext_vector_type(8))) short s16x8;
typedef __attribute__((ext_vector_type(4))) float f32x4;
typedef __attribute__((ext_vector_type(4))) int   i32x4;

struct TrueT  { static constexpr bool value = true;  };
struct FalseT { static constexpr bool value = false; };

static __device__ __forceinline__ f32x4 mfma_bf16(s16x8 a, s16x8 b, f32x4 c) {
    return __builtin_amdgcn_mfma_f32_16x16x32_bf16(a, b, c, 0, 0, 0);
}

static __device__ __forceinline__ unsigned short f32_to_bf16(float f) {
    unsigned int u = __float_as_uint(f);
    u = (u + 0x7fffu + ((u >> 16) & 1u)) >> 16;
    return (unsigned short)u;
}

// packed f32x2 -> bf16x2 (T12; lo -> bits[15:0], hi -> bits[31:16])
static __device__ __forceinline__ unsigned int cvtpk(float lo, float hi) {
    unsigned int r;
    asm("v_cvt_pk_bf16_f32 %0, %1, %2" : "=v"(r) : "v"(lo), "v"(hi));
    return r;
}

static __device__ __forceinline__ unsigned long long pack4(float a, float b,
                                                           float c, float d) {
    return (unsigned long long)cvtpk(a, b) |
           ((unsigned long long)cvtpk(c, d) << 32);
}

static __device__ __forceinline__ void gload16(const void* g, void* l) {
    __builtin_amdgcn_global_load_lds(
        (const __attribute__((address_space(1))) void*)g,
        (__attribute__((address_space(3))) void*)l, 16, 0, 0);
}

// ---------------- conversion kernels ----------------

__global__ void cvt_f32_bf16(const float* __restrict__ in,
                             unsigned short* __restrict__ out, int n4) {
    int i = blockIdx.x * blockDim.x + threadIdx.x;
    if (i < n4) {
        float4 v = ((const float4*)in)[i];
        ushort4 o;
        o.x = f32_to_bf16(v.x); o.y = f32_to_bf16(v.y);
        o.z = f32_to_bf16(v.z); o.w = f32_to_bf16(v.w);
        ((ushort4*)out)[i] = o;
    }
}

// in: [K][N] f32  ->  out: [N][K] bf16
__global__ __launch_bounds__(256) void transpose_cvt(
    const float* __restrict__ in, unsigned short* __restrict__ out, int K, int N) {
    __shared__ float tile[32][33];
    int n0 = blockIdx.x * 32, k0 = blockIdx.y * 32;
    int tx = threadIdx.x & 31, ty = threadIdx.x >> 5; // 32 x 8
    #pragma unroll
    for (int i = 0; i < 4; i++) {
        int k = ty + i * 8;
        tile[k][tx] = in[(size_t)(k0 + k) * N + (n0 + tx)];
    }
    __syncthreads();
    #pragma unroll
    for (int i = 0; i < 4; i++) {
        int n = ty + i * 8;
        out[(size_t)(n0 + n) * K + (k0 + tx)] = f32_to_bf16(tile[tx][n]);
    }
}

// ============ 256x256 8-phase QKV GEMM (T2+T3+T4+T5) ============

__global__ __launch_bounds__(512, 2) void gemm256_qkv(
    const unsigned short* __restrict__ A,    // [8192][1024]
    const unsigned short* __restrict__ Bt,   // [3072][1024]
    const float* __restrict__ bias,          // [3072]
    unsigned short* __restrict__ q_buf, unsigned short* __restrict__ k_buf,
    unsigned short* __restrict__ vT) {
    extern __shared__ float4 smv[];
    char* sm = (char*)smv;
    const int K = 1024, NT = 16;
    const int tid = threadIdx.x;
    const int lane = tid & 63, w = tid >> 6;
    const int wm = w >> 2, wn = w & 3;
    const int lq = lane & 15, lk = lane >> 4;
    const int m0 = blockIdx.y * 256, n0 = blockIdx.x * 256;

    const unsigned short* GA = A + (size_t)m0 * K;
    const unsigned short* GB = Bt + (size_t)n0 * K;

    auto stage = [&](const unsigned short* G, int mat, int t, int half) {
        char* base = sm + (t & 1) * 65536 + mat * 32768 + half * 16384;
        const unsigned short* g0 = G + (size_t)(half * 128) * K + t * 64;
        #pragma unroll
        for (int j = 0; j < 2; j++) {
            int c = j * 512 + tid;
            int row = c >> 3, cc = c & 7;
            int cg = cc ^ (row & 7);                       // inverse swizzle on src
            gload16(g0 + (size_t)row * K + cg * 8,
                    base + (j * 512 + w * 64) * 16);        // wave-uniform dest
        }
    };
    auto lda = [&](int buf, int mf, int ks) -> s16x8 {
        int byte = (((mf * 16 + lq) * 128 + ks * 64 + lk * 16)) ^ ((lq & 7) << 4);
        return *(const s16x8*)(sm + buf * 65536 + wm * 16384 + byte);
    };
    auto ldb = [&](int buf, int nf, int ks) -> s16x8 {
        int byte = ((((wn & 1) * 64 + nf * 16 + lq) * 128 + ks * 64 + lk * 16)) ^
                   ((lq & 7) << 4);
        return *(const s16x8*)(sm + buf * 65536 + 32768 + (wn >> 1) * 16384 + byte);
    };

    f32x4 acc[8][4];
    #pragma unroll
    for (int m = 0; m < 8; m++)
        #pragma unroll
        for (int n = 0; n < 4; n++)
            #pragma unroll
            for (int r = 0; r < 4; r++) acc[m][n][r] = 0.f;

    stage(GA, 0, 0, 0); stage(GA, 0, 0, 1); stage(GB, 1, 0, 0); stage(GB, 1, 0, 1);
    stage(GA, 0, 1, 0); stage(GA, 0, 1, 1); stage(GB, 1, 1, 0);
    asm volatile("s_waitcnt vmcnt(6)" ::: "memory");
    __builtin_amdgcn_s_barrier();

    s16x8 alo[4][2], ahi[4][2], blo[2][2], bhi[2][2];
    for (int t = 0; t < NT; t++) {
        const int buf = t & 1;
        #pragma unroll
        for (int mf = 0; mf < 4; mf++)
            #pragma unroll
            for (int ks = 0; ks < 2; ks++) alo[mf][ks] = lda(buf, mf, ks);
        #pragma unroll
        for (int nf = 0; nf < 2; nf++)
            #pragma unroll
            for (int ks = 0; ks < 2; ks++) blo[nf][ks] = ldb(buf, nf, ks);
        if (t + 1 < NT) stage(GB, 1, t + 1, 1);
        __builtin_amdgcn_s_barrier();
        asm volatile("s_waitcnt lgkmcnt(0)" ::: "memory");
        __builtin_amdgcn_s_setprio(1);
        #pragma unroll
        for (int mf = 0; mf < 4; mf++)
            #pragma unroll
            for (int nf = 0; nf < 2; nf++)
                #pragma unroll
                for (int ks = 0; ks < 2; ks++)
                    acc[mf][nf] = mfma_bf16(alo[mf][ks], blo[nf][ks], acc[mf][nf]);
        __builtin_amdgcn_s_setprio(0);
        __builtin_amdgcn_s_barrier();
        #pragma unroll
        for (int nf = 0; nf < 2; nf++)
            #pragma unroll
            for (int ks = 0; ks < 2; ks++) bhi[nf][ks] = ldb(buf, 2 + nf, ks);
        __builtin_amdgcn_s_barrier();
        asm volatile("s_waitcnt lgkmcnt(0)" ::: "memory");
        __builtin_amdgcn_s_setprio(1);
        #pragma unroll
        for (int mf = 0; mf < 4; mf++)
            #pragma unroll
            for (int nf = 0; nf < 2; nf++)
                #pragma unroll
                for (int ks = 0; ks < 2; ks++)
                    acc[mf][2 + nf] = mfma_bf16(alo[mf][ks], bhi[nf][ks], acc[mf][2 + nf]);
        __builtin_amdgcn_s_setprio(0);
        __builtin_amdgcn_s_barrier();
        #pragma unroll
        for (int mf = 0; mf < 4; mf++)
            #pragma unroll
            for (int ks = 0; ks < 2; ks++) ahi[mf][ks] = lda(buf, 4 + mf, ks);
        if (t + 2 < NT) stage(GB, 1, t + 2, 0);
        __builtin_amdgcn_s_barrier();
        asm volatile("s_waitcnt lgkmcnt(0)" ::: "memory");
        __builtin_amdgcn_s_setprio(1);
        #pragma unroll
        for (int mf = 0; mf < 4; mf++)
            #pragma unroll
            for (int nf = 0; nf < 2; nf++)
                #pragma unroll
                for (int ks = 0; ks < 2; ks++)
                    acc[4 + mf][nf] = mfma_bf16(ahi[mf][ks], blo[nf][ks], acc[4 + mf][nf]);
        __builtin_amdgcn_s_setprio(0);
        __builtin_amdgcn_s_barrier();
        if (t + 2 < NT) { stage(GA, 0, t + 2, 0); stage(GA, 0, t + 2, 1); }
        __builtin_amdgcn_s_barrier();
        asm volatile("s_waitcnt lgkmcnt(0)" ::: "memory");
        __builtin_amdgcn_s_setprio(1);
        #pragma unroll
        for (int mf = 0; mf < 4; mf++)
            #pragma unroll
            for (int nf = 0; nf < 2; nf++)
                #pragma unroll
                for (int ks = 0; ks < 2; ks++)
                    acc[4 + mf][2 + nf] = mfma_bf16(ahi[mf][ks], bhi[nf][ks], acc[4 + mf][2 + nf]);
        __builtin_amdgcn_s_setprio(0);
        if (t + 2 < NT) {
            asm volatile("s_waitcnt vmcnt(6)" ::: "memory");
        } else if (t + 1 < NT) {
            asm volatile("s_waitcnt vmcnt(0)" ::: "memory");
        }
        __builtin_amdgcn_s_barrier();
    }

    const int rowb = m0 + wm * 128 + lk * 4;
    const int colb = n0 + wn * 64 + lq;
    if (n0 < 1024) {
        #pragma unroll
        for (int mf = 0; mf < 8; mf++) {
            int row = rowb + mf * 16;
            #pragma unroll
            for (int nf = 0; nf < 4; nf++) {
                int col = colb + nf * 16;
                float bv = bias[col];
                #pragma unroll
                for (int r = 0; r < 4; r++)
                    q_buf[(size_t)(row + r) * 1024 + col] =
                        f32_to_bf16((acc[mf][nf][r] + bv) * SCALE_L2E);
            }
        }
    } else if (n0 < 2048) {
        #pragma unroll
        for (int mf = 0; mf < 8; mf++) {
            int row = rowb + mf * 16;
            #pragma unroll
            for (int nf = 0; nf < 4; nf++) {
                int col = colb + nf * 16;
                float bv = bias[col];
                #pragma unroll
                for (int r = 0; r < 4; r++)
                    k_buf[(size_t)(row + r) * 1024 + (col - 1024)] =
                        f32_to_bf16(acc[mf][nf][r] + bv);
            }
        }
    } else {
        #pragma unroll
        for (int mf = 0; mf < 8; mf++) {
            int row = rowb + mf * 16;
            int bb = row >> 11, pos = row & 2047;
            #pragma unroll
            for (int nf = 0; nf < 4; nf++) {
                int col = colb + nf * 16;
                int dg = col - 2048;
                float bv = bias[col];
                unsigned long long pk =
                    pack4(acc[mf][nf][0] + bv, acc[mf][nf][1] + bv,
                          acc[mf][nf][2] + bv, acc[mf][nf][3] + bv);
                *(unsigned long long*)(vT +
                    ((size_t)((bb * 16 + (dg >> 6)) * 64 + (dg & 63))) * 2048 + pos) = pk;
            }
        }
    }
}

// ---------------- GEMM (128x128) for out-proj ----------------

__global__ __launch_bounds__(256) void gemm_bf16_f32(
    const unsigned short* __restrict__ A,   // [M][K] bf16
    const unsigned short* __restrict__ Bt,  // [N][K] bf16
    const float* __restrict__ bias,         // [N] f32
    float* __restrict__ C, int M, int N, int K) {
    __shared__ __align__(16) unsigned short As[2][128][32];
    __shared__ __align__(16) unsigned short Bs[2][128][32];

    const int tid = threadIdx.x;
    const int m0 = blockIdx.y * 128;
    const int n0 = blockIdx.x * 128;
    const int lane = tid & 63, w4 = tid >> 6;
    const int wr = w4 >> 1, wc = w4 & 1;
    const int lq = lane & 15, lk = lane >> 4;

    const int srow = lane >> 2;
    const int sk = (lane & 3) * 8;
    const unsigned short* ap = A  + (size_t)(m0 + w4 * 16 + srow) * K + sk;
    const unsigned short* bp = Bt + (size_t)(n0 + w4 * 16 + srow) * K + sk;

    f32x4 acc[4][4];
    #pragma unroll
    for (int m = 0; m < 4; m++)
        #pragma unroll
        for (int n = 0; n < 4; n++)
            #pragma unroll
            for (int r = 0; r < 4; r++) acc[m][n][r] = 0.f;

    gload16(ap,                  &As[0][w4 * 16][0]);
    gload16(ap + (size_t)64 * K, &As[0][64 + w4 * 16][0]);
    gload16(bp,                  &Bs[0][w4 * 16][0]);
    gload16(bp + (size_t)64 * K, &Bs[0][64 + w4 * 16][0]);
    __syncthreads();

    int buf = 0;
    for (int k0 = 0; k0 < K; k0 += 32) {
        if (k0 + 32 < K) {
            const unsigned short* ap2 = ap + k0 + 32;
            const unsigned short* bp2 = bp + k0 + 32;
            gload16(ap2,                  &As[buf ^ 1][w4 * 16][0]);
            gload16(ap2 + (size_t)64 * K, &As[buf ^ 1][64 + w4 * 16][0]);
            gload16(bp2,                  &Bs[buf ^ 1][w4 * 16][0]);
            gload16(bp2 + (size_t)64 * K, &Bs[buf ^ 1][64 + w4 * 16][0]);
        }
        s16x8 af[4], bfr[4];
        #pragma unroll
        for (int m = 0; m < 4; m++)
            af[m] = *(const s16x8*)(&As[buf][wr * 64 + m * 16 + lq][lk * 8]);
        #pragma unroll
        for (int n = 0; n < 4; n++)
            bfr[n] = *(const s16x8*)(&Bs[buf][wc * 64 + n * 16 + lq][lk * 8]);
        #pragma unroll
        for (int m = 0; m < 4; m++)
            #pragma unroll
            for (int n = 0; n < 4; n++)
                acc[m][n] = mfma_bf16(af[m], bfr[n], acc[m][n]);
        __syncthreads();
        buf ^= 1;
    }

    #pragma unroll
    for (int m = 0; m < 4; m++) {
        int row = m0 + wr * 64 + m * 16 + lk * 4;
        #pragma unroll
        for (int n = 0; n < 4; n++) {
            int col = n0 + wc * 64 + n * 16 + lq;
            float bv = bias[col];
            #pragma unroll
            for (int r = 0; r < 4; r++)
                C[(size_t)(row + r) * N + col] = acc[m][n][r] + bv;
        }
    }
}

// ---------------- flash attention: paired dual-stream q-tiles ----------------
// grid: 1024 1D blocks; bid = pj*64 + bh  (bid%8 = bh%8 -> same-bh on one XCD).
// Block pj processes q-tile A = pj (nA = pj+1 kv-tiles) and q-tile B = 31-pj
// (nB = 32-pj) over ONE shared kv stream: uniform 33 units of work per block.
// K/V ds_reads are shared by both streams' MFMAs; streams are independent
// chains (in-wave ILP). LDS: Ks/Vs 16KB + PwA/PwB 16KB = 32KB.

__global__ __launch_bounds__(256, 4) void attn_kernel(
    const unsigned short* __restrict__ q_buf,
    const unsigned short* __restrict__ k_buf,
    const unsigned short* __restrict__ vT,
    unsigned short* __restrict__ out) {
    __shared__ __align__(16) char lds[32768];
    char* Ks = lds;
    char* Vs = lds + 8192;

    const int bid = blockIdx.x;
    const int bh = bid & 63;
    const int pj = bid >> 6;               // 0..15
    const int b = bh >> 4, h = bh & 15;
    const int tid = threadIdx.x, lane = tid & 63, w = tid >> 6;
    const int lq = lane & 15, lk = lane >> 4;
    char* PwA = lds + 16384 + w * 2048;
    char* PwB = lds + 24576 + w * 2048;

    const int nA = pj + 1, nB = 32 - pj;
    const int qgA = pj * 64 + w * 16 + lq;
    const int qgB = (31 - pj) * 64 + w * 16 + lq;

    const unsigned short* qpA = q_buf + ((size_t)b * LSEQ + qgA) * 1024 + h * 64;
    const unsigned short* qpB = q_buf + ((size_t)b * LSEQ + qgB) * 1024 + h * 64;
    const s16x8 qA0 = *(const s16x8*)(qpA + lk * 8);
    const s16x8 qA1 = *(const s16x8*)(qpA + 32 + lk * 8);
    const s16x8 qB0 = *(const s16x8*)(qpB + lk * 8);
    const s16x8 qB1 = *(const s16x8*)(qpB + 32 + lk * 8);

    const int srow = tid >> 3, sch = tid & 7;
    const int sby0 = (srow * 128 + sch * 16) ^ ((srow & 7) << 4);
    const int sby1 = ((srow + 32) * 128 + sch * 16) ^ ((srow & 7) << 4);
    const int swzA = (lq & 7) << 4;

    const unsigned short* kp =
        k_buf + (size_t)b * LSEQ * 1024 + h * 64 + (size_t)srow * 1024 + sch * 8;
    const unsigned short* vp =
        vT + (size_t)bh * 64 * 2048 + (size_t)srow * 2048 + sch * 8;

    float mA = -1e30f, lA = 0.f, mB = -1e30f, lB = 0.f;
    f32x4 oA[4], oB[4];
    #pragma unroll
    for (int n = 0; n < 4; n++)
        #pragma unroll
        for (int r = 0; r < 4; r++) { oA[n][r] = 0.f; oB[n][r] = 0.f; }

    i32x4 r0 = *(const i32x4*)kp;
    i32x4 r1 = *(const i32x4*)(kp + (size_t)32 * 1024);
    i32x4 r2 = *(const i32x4*)vp;
    i32x4 r3 = *(const i32x4*)(vp + (size_t)32 * 2048);

    for (int kvb = 0; kvb < nB; kvb++) {
        *(i32x4*)(Ks + sby0) = r0;
        *(i32x4*)(Ks + sby1) = r1;
        *(i32x4*)(Vs + sby0) = r2;
        *(i32x4*)(Vs + sby1) = r3;
        __syncthreads();
        if (kvb + 1 < nB) {   // T14 prefetch: hides under dual compute
            kp += 64 * 1024;
            vp += 64;
            r0 = *(const i32x4*)kp;
            r1 = *(const i32x4*)(kp + (size_t)32 * 1024);
            r2 = *(const i32x4*)vp;
            r3 = *(const i32x4*)(vp + (size_t)32 * 2048);
        }

        auto tile = [&](auto doa_t) {
            constexpr bool DOA = decltype(doa_t)::value;
            f32x4 sA[4], sB[4];
            #pragma unroll
            for (int n = 0; n < 4; n++)
                #pragma unroll
                for (int r = 0; r < 4; r++) {
                    sB[n][r] = 0.f;
                    if (DOA) sA[n][r] = 0.f;
                }
            __builtin_amdgcn_s_setprio(1);
            #pragma unroll
            for (int n = 0; n < 4; n++) {
                const int rb = (n * 16 + lq) * 128;
                s16x8 a0 = *(const s16x8*)(Ks + ((rb + lk * 16) ^ swzA));
                s16x8 a1 = *(const s16x8*)(Ks + ((rb + 64 + lk * 16) ^ swzA));
                sB[n] = mfma_bf16(a0, qB0, sB[n]);
                sB[n] = mfma_bf16(a1, qB1, sB[n]);
                if (DOA) {
                    sA[n] = mfma_bf16(a0, qA0, sA[n]);
                    sA[n] = mfma_bf16(a1, qA1, sA[n]);
                }
            }
            __builtin_amdgcn_s_setprio(0);
            const int kv0 = kvb * 64;
            if (kvb == nB - 1) {
                #pragma unroll
                for (int n = 0; n < 4; n++)
                    #pragma unroll
                    for (int r = 0; r < 4; r++)
                        if (kv0 + n * 16 + lk * 4 + r > qgB) sB[n][r] = -1e30f;
            }
            if (DOA && kvb == nA - 1) {
                #pragma unroll
                for (int n = 0; n < 4; n++)
                    #pragma unroll
                    for (int r = 0; r < 4; r++)
                        if (kv0 + n * 16 + lk * 4 + r > qgA) sA[n][r] = -1e30f;
            }
            unsigned long long pkB[4], pkA[4];
            {   // softmax B (exp2 domain; q pre-scaled)
                float mx = sB[0][0];
                #pragma unroll
                for (int n = 0; n < 4; n++)
                    #pragma unroll
                    for (int r = 0; r < 4; r++) mx = fmaxf(mx, sB[n][r]);
                mx = fmaxf(mx, __shfl_xor(mx, 16, 64));
                mx = fmaxf(mx, __shfl_xor(mx, 32, 64));
                if (!__all(mx <= mB + 8.f)) {   // T13 defer-max
                    const float mnew = fmaxf(mB, mx);
                    const float corr = __builtin_amdgcn_exp2f(mB - mnew);
                    mB = mnew; lB *= corr;
                    #pragma unroll
                    for (int n = 0; n < 4; n++)
                        #pragma unroll
                        for (int r = 0; r < 4; r++) oB[n][r] *= corr;
                }
                float sum = 0.f;
                #pragma unroll
                for (int n = 0; n < 4; n++) {
                    float p0 = __builtin_amdgcn_exp2f(sB[n][0] - mB);
                    float p1 = __builtin_amdgcn_exp2f(sB[n][1] - mB);
                    float p2 = __builtin_amdgcn_exp2f(sB[n][2] - mB);
                    float p3 = __builtin_amdgcn_exp2f(sB[n][3] - mB);
                    sum += (p0 + p1) + (p2 + p3);
                    pkB[n] = pack4(p0, p1, p2, p3);
                }
                lB += sum;
            }
            if (DOA) {   // softmax A
                float mx = sA[0][0];
                #pragma unroll
                for (int n = 0; n < 4; n++)
                    #pragma unroll
                    for (int r = 0; r < 4; r++) mx = fmaxf(mx, sA[n][r]);
                mx = fmaxf(mx, __shfl_xor(mx, 16, 64));
                mx = fmaxf(mx, __shfl_xor(mx, 32, 64));
                if (!__all(mx <= mA + 8.f)) {
                    const float mnew = fmaxf(mA, mx);
                    const float corr = __builtin_amdgcn_exp2f(mA - mnew);
                    mA = mnew; lA *= corr;
                    #pragma unroll
                    for (int n = 0; n < 4; n++)
                        #pragma unroll
                        for (int r = 0; r < 4; r++) oA[n][r] *= corr;
                }
                float sum = 0.f;
                #pragma unroll
                for (int n = 0; n < 4; n++) {
                    float p0 = __builtin_amdgcn_exp2f(sA[n][0] - mA);
                    float p1 = __builtin_amdgcn_exp2f(sA[n][1] - mA);
                    float p2 = __builtin_amdgcn_exp2f(sA[n][2] - mA);
                    float p3 = __builtin_amdgcn_exp2f(sA[n][3] - mA);
                    sum += (p0 + p1) + (p2 + p3);
                    pkA[n] = pack4(p0, p1, p2, p3);
                }
                lA += sum;
            }
            #pragma unroll
            for (int n = 0; n < 4; n++) {
                const int pb_off = (lq * 128 + n * 32 + lk * 8) ^ swzA;
                *(unsigned long long*)(PwB + pb_off) = pkB[n];
                if (DOA) *(unsigned long long*)(PwA + pb_off) = pkA[n];
            }
            asm volatile("s_waitcnt lgkmcnt(0)" ::: "memory");
            __builtin_amdgcn_s_setprio(1);
            #pragma unroll
            for (int kk = 0; kk < 2; kk++) {
                const int p_off = (lq * 128 + kk * 64 + lk * 16) ^ swzA;
                s16x8 pbB = *(const s16x8*)(PwB + p_off);
                s16x8 pbA;
                if (DOA) pbA = *(const s16x8*)(PwA + p_off);
                #pragma unroll
                for (int n = 0; n < 4; n++) {
                    s16x8 vf = *(const s16x8*)(Vs +
                        (((n * 16 + lq) * 128 + kk * 64 + lk * 16) ^ swzA));
                    oB[n] = mfma_bf16(vf, pbB, oB[n]);
                    if (DOA) oA[n] = mfma_bf16(vf, pbA, oA[n]);
                }
            }
            __builtin_amdgcn_s_setprio(0);
        };
        if (kvb < nA) tile(TrueT{}); else tile(FalseT{});

        // raw barrier: LDS reads already consumed; prefetch stays in flight
        asm volatile("s_barrier" ::: "memory");
    }

    lB += __shfl_xor(lB, 16, 64);
    lB += __shfl_xor(lB, 32, 64);
    lA += __shfl_xor(lA, 16, 64);
    lA += __shfl_xor(lA, 32, 64);
    const float invB = 1.f / lB;
    const float invA = 1.f / lA;
    unsigned short* opB = out + ((size_t)b * LSEQ + qgB) * 1024 + h * 64;
    unsigned short* opA = out + ((size_t)b * LSEQ + qgA) * 1024 + h * 64;
    #pragma unroll
    for (int n = 0; n < 4; n++) {
        *(unsigned long long*)(opB + n * 16 + lk * 4) =
            pack4(oB[n][0] * invB, oB[n][1] * invB, oB[n][2] * invB, oB[n][3] * invB);
        *(unsigned long long*)(opA + n * 16 + lk * 4) =
            pack4(oA[n][0] * invA, oA[n][1] * invA, oA[n][2] * invA, oA[n][3] * invA);
    }
}

// ---------------- launch ----------------

extern "C" void kernel_launch(void* const* d_in, const int* in_sizes, int n_in,
                              void* d_out, int out_size, void* d_ws, size_t ws_size,
                              hipStream_t stream) {
    const float* x     = (const float*)d_in[0];
    const float* W_qkv = (const float*)d_in[1];
    const float* b_qkv = (const float*)d_in[2];
    const float* W_out = (const float*)d_in[3];
    const float* b_out = (const float*)d_in[4];
    float* out = (float*)d_out;

    char* p = (char*)d_ws;
    unsigned short* x_bf   = (unsigned short*)p; p += (size_t)NROWS * D_MODEL * 2;
    unsigned short* wqkv_t = (unsigned short*)p; p += (size_t)3 * D_MODEL * D_MODEL * 2;
    unsigned short* wout_t = (unsigned short*)p; p += (size_t)D_MODEL * D_MODEL * 2;
    unsigned short* q_buf  = (unsigned short*)p; p += (size_t)NROWS * D_MODEL * 2;
    unsigned short* k_buf  = (unsigned short*)p; p += (size_t)NROWS * D_MODEL * 2;
    unsigned short* vT     = (unsigned short*)p; p += (size_t)NROWS * D_MODEL * 2;
    unsigned short* attn   = (unsigned short*)p;

    hipFuncSetAttribute((const void*)gemm256_qkv,
                        hipFuncAttributeMaxDynamicSharedMemorySize, 131072);

    int n4 = NROWS * D_MODEL / 4;
    hipLaunchKernelGGL(cvt_f32_bf16, dim3((n4 + 255) / 256), dim3(256), 0, stream,
                       x, x_bf, n4);
    hipLaunchKernelGGL(transpose_cvt, dim3(3 * D_MODEL / 32, D_MODEL / 32), dim3(256),
                       0, stream, W_qkv, wqkv_t, D_MODEL, 3 * D_MODEL);
    hipLaunchKernelGGL(transpose_cvt, dim3(D_MODEL / 32, D_MODEL / 32), dim3(256),
                       0, stream, W_out, wout_t, D_MODEL, D_MODEL);
    hipLaunchKernelGGL(gemm256_qkv, dim3(3 * D_MODEL / 256, NROWS / 256),
                       dim3(512), 131072, stream, x_bf, wqkv_t, b_qkv,
                       q_buf, k_buf, vT);
    hipLaunchKernelGGL(attn_kernel, dim3(16 * 64), dim3(256), 0, stream,
                       q_buf, k_buf, vT, attn);
    hipLaunchKernelGGL(gemm_bf16_f32, dim3(D_MODEL / 128, NROWS / 128),
                       dim3(256), 0, stream, attn, wout_t, b_out, out,
                       NROWS, D_MODEL, D_MODEL);
}

// Round 7
// 272.577 us; speedup vs baseline: 1.5313x; 1.5313x over previous
//
#include <hip/hip_runtime.h>
#include <hip/hip_bf16.h>
#include <stdint.h>

#define D_MODEL 1024
#define NH 16
#define HD 64
#define LSEQ 2048
#define BATCH 4
#define NROWS (BATCH * LSEQ) /* 8192 */
#define SCALE_L2E 0.18033688011112042f /* 0.125 * log2(e) */

typedef __attribute__((ext_vector_type(8))) short s16x8;
typedef __attribute__((ext_vector_type(4))) float f32x4;
typedef __attribute__((ext_vector_type(4))) int   i32x4;

static __device__ __forceinline__ f32x4 mfma_bf16(s16x8 a, s16x8 b, f32x4 c) {
    return __builtin_amdgcn_mfma_f32_16x16x32_bf16(a, b, c, 0, 0, 0);
}

static __device__ __forceinline__ unsigned short f32_to_bf16(float f) {
    unsigned int u = __float_as_uint(f);
    u = (u + 0x7fffu + ((u >> 16) & 1u)) >> 16;
    return (unsigned short)u;
}

// packed f32x2 -> bf16x2 (T12; lo -> bits[15:0], hi -> bits[31:16])
static __device__ __forceinline__ unsigned int cvtpk(float lo, float hi) {
    unsigned int r;
    asm("v_cvt_pk_bf16_f32 %0, %1, %2" : "=v"(r) : "v"(lo), "v"(hi));
    return r;
}

static __device__ __forceinline__ unsigned long long pack4(float a, float b,
                                                           float c, float d) {
    return (unsigned long long)cvtpk(a, b) |
           ((unsigned long long)cvtpk(c, d) << 32);
}

static __device__ __forceinline__ void gload16(const void* g, void* l) {
    __builtin_amdgcn_global_load_lds(
        (const __attribute__((address_space(1))) void*)g,
        (__attribute__((address_space(3))) void*)l, 16, 0, 0);
}

// ---------------- conversion kernels ----------------

__global__ void cvt_f32_bf16(const float* __restrict__ in,
                             unsigned short* __restrict__ out, int n4) {
    int i = blockIdx.x * blockDim.x + threadIdx.x;
    if (i < n4) {
        float4 v = ((const float4*)in)[i];
        ushort4 o;
        o.x = f32_to_bf16(v.x); o.y = f32_to_bf16(v.y);
        o.z = f32_to_bf16(v.z); o.w = f32_to_bf16(v.w);
        ((ushort4*)out)[i] = o;
    }
}

// in: [K][N] f32  ->  out: [N][K] bf16
__global__ __launch_bounds__(256) void transpose_cvt(
    const float* __restrict__ in, unsigned short* __restrict__ out, int K, int N) {
    __shared__ float tile[32][33];
    int n0 = blockIdx.x * 32, k0 = blockIdx.y * 32;
    int tx = threadIdx.x & 31, ty = threadIdx.x >> 5; // 32 x 8
    #pragma unroll
    for (int i = 0; i < 4; i++) {
        int k = ty + i * 8;
        tile[k][tx] = in[(size_t)(k0 + k) * N + (n0 + tx)];
    }
    __syncthreads();
    #pragma unroll
    for (int i = 0; i < 4; i++) {
        int n = ty + i * 8;
        out[(size_t)(n0 + n) * K + (k0 + tx)] = f32_to_bf16(tile[tx][n]);
    }
}

// ============ 256x256 8-phase QKV GEMM (T2+T3+T4+T5) ============

__global__ __launch_bounds__(512, 2) void gemm256_qkv(
    const unsigned short* __restrict__ A,    // [8192][1024]
    const unsigned short* __restrict__ Bt,   // [3072][1024]
    const float* __restrict__ bias,          // [3072]
    unsigned short* __restrict__ q_buf, unsigned short* __restrict__ k_buf,
    unsigned short* __restrict__ vT) {
    extern __shared__ float4 smv[];
    char* sm = (char*)smv;
    const int K = 1024, NT = 16;
    const int tid = threadIdx.x;
    const int lane = tid & 63, w = tid >> 6;
    const int wm = w >> 2, wn = w & 3;
    const int lq = lane & 15, lk = lane >> 4;
    const int m0 = blockIdx.y * 256, n0 = blockIdx.x * 256;

    const unsigned short* GA = A + (size_t)m0 * K;
    const unsigned short* GB = Bt + (size_t)n0 * K;

    auto stage = [&](const unsigned short* G, int mat, int t, int half) {
        char* base = sm + (t & 1) * 65536 + mat * 32768 + half * 16384;
        const unsigned short* g0 = G + (size_t)(half * 128) * K + t * 64;
        #pragma unroll
        for (int j = 0; j < 2; j++) {
            int c = j * 512 + tid;
            int row = c >> 3, cc = c & 7;
            int cg = cc ^ (row & 7);                       // inverse swizzle on src
            gload16(g0 + (size_t)row * K + cg * 8,
                    base + (j * 512 + w * 64) * 16);        // wave-uniform dest
        }
    };
    auto lda = [&](int buf, int mf, int ks) -> s16x8 {
        int byte = (((mf * 16 + lq) * 128 + ks * 64 + lk * 16)) ^ ((lq & 7) << 4);
        return *(const s16x8*)(sm + buf * 65536 + wm * 16384 + byte);
    };
    auto ldb = [&](int buf, int nf, int ks) -> s16x8 {
        int byte = ((((wn & 1) * 64 + nf * 16 + lq) * 128 + ks * 64 + lk * 16)) ^
                   ((lq & 7) << 4);
        return *(const s16x8*)(sm + buf * 65536 + 32768 + (wn >> 1) * 16384 + byte);
    };

    f32x4 acc[8][4];
    #pragma unroll
    for (int m = 0; m < 8; m++)
        #pragma unroll
        for (int n = 0; n < 4; n++)
            #pragma unroll
            for (int r = 0; r < 4; r++) acc[m][n][r] = 0.f;

    stage(GA, 0, 0, 0); stage(GA, 0, 0, 1); stage(GB, 1, 0, 0); stage(GB, 1, 0, 1);
    stage(GA, 0, 1, 0); stage(GA, 0, 1, 1); stage(GB, 1, 1, 0);
    asm volatile("s_waitcnt vmcnt(6)" ::: "memory");
    __builtin_amdgcn_s_barrier();

    s16x8 alo[4][2], ahi[4][2], blo[2][2], bhi[2][2];
    for (int t = 0; t < NT; t++) {
        const int buf = t & 1;
        #pragma unroll
        for (int mf = 0; mf < 4; mf++)
            #pragma unroll
            for (int ks = 0; ks < 2; ks++) alo[mf][ks] = lda(buf, mf, ks);
        #pragma unroll
        for (int nf = 0; nf < 2; nf++)
            #pragma unroll
            for (int ks = 0; ks < 2; ks++) blo[nf][ks] = ldb(buf, nf, ks);
        if (t + 1 < NT) stage(GB, 1, t + 1, 1);
        __builtin_amdgcn_s_barrier();
        asm volatile("s_waitcnt lgkmcnt(0)" ::: "memory");
        __builtin_amdgcn_s_setprio(1);
        #pragma unroll
        for (int mf = 0; mf < 4; mf++)
            #pragma unroll
            for (int nf = 0; nf < 2; nf++)
                #pragma unroll
                for (int ks = 0; ks < 2; ks++)
                    acc[mf][nf] = mfma_bf16(alo[mf][ks], blo[nf][ks], acc[mf][nf]);
        __builtin_amdgcn_s_setprio(0);
        __builtin_amdgcn_s_barrier();
        #pragma unroll
        for (int nf = 0; nf < 2; nf++)
            #pragma unroll
            for (int ks = 0; ks < 2; ks++) bhi[nf][ks] = ldb(buf, 2 + nf, ks);
        __builtin_amdgcn_s_barrier();
        asm volatile("s_waitcnt lgkmcnt(0)" ::: "memory");
        __builtin_amdgcn_s_setprio(1);
        #pragma unroll
        for (int mf = 0; mf < 4; mf++)
            #pragma unroll
            for (int nf = 0; nf < 2; nf++)
                #pragma unroll
                for (int ks = 0; ks < 2; ks++)
                    acc[mf][2 + nf] = mfma_bf16(alo[mf][ks], bhi[nf][ks], acc[mf][2 + nf]);
        __builtin_amdgcn_s_setprio(0);
        __builtin_amdgcn_s_barrier();
        #pragma unroll
        for (int mf = 0; mf < 4; mf++)
            #pragma unroll
            for (int ks = 0; ks < 2; ks++) ahi[mf][ks] = lda(buf, 4 + mf, ks);
        if (t + 2 < NT) stage(GB, 1, t + 2, 0);
        __builtin_amdgcn_s_barrier();
        asm volatile("s_waitcnt lgkmcnt(0)" ::: "memory");
        __builtin_amdgcn_s_setprio(1);
        #pragma unroll
        for (int mf = 0; mf < 4; mf++)
            #pragma unroll
            for (int nf = 0; nf < 2; nf++)
                #pragma unroll
                for (int ks = 0; ks < 2; ks++)
                    acc[4 + mf][nf] = mfma_bf16(ahi[mf][ks], blo[nf][ks], acc[4 + mf][nf]);
        __builtin_amdgcn_s_setprio(0);
        __builtin_amdgcn_s_barrier();
        if (t + 2 < NT) { stage(GA, 0, t + 2, 0); stage(GA, 0, t + 2, 1); }
        __builtin_amdgcn_s_barrier();
        asm volatile("s_waitcnt lgkmcnt(0)" ::: "memory");
        __builtin_amdgcn_s_setprio(1);
        #pragma unroll
        for (int mf = 0; mf < 4; mf++)
            #pragma unroll
            for (int nf = 0; nf < 2; nf++)
                #pragma unroll
                for (int ks = 0; ks < 2; ks++)
                    acc[4 + mf][2 + nf] = mfma_bf16(ahi[mf][ks], bhi[nf][ks], acc[4 + mf][2 + nf]);
        __builtin_amdgcn_s_setprio(0);
        if (t + 2 < NT) {
            asm volatile("s_waitcnt vmcnt(6)" ::: "memory");
        } else if (t + 1 < NT) {
            asm volatile("s_waitcnt vmcnt(0)" ::: "memory");
        }
        __builtin_amdgcn_s_barrier();
    }

    const int rowb = m0 + wm * 128 + lk * 4;
    const int colb = n0 + wn * 64 + lq;
    if (n0 < 1024) {
        #pragma unroll
        for (int mf = 0; mf < 8; mf++) {
            int row = rowb + mf * 16;
            #pragma unroll
            for (int nf = 0; nf < 4; nf++) {
                int col = colb + nf * 16;
                float bv = bias[col];
                #pragma unroll
                for (int r = 0; r < 4; r++)
                    q_buf[(size_t)(row + r) * 1024 + col] =
                        f32_to_bf16((acc[mf][nf][r] + bv) * SCALE_L2E);
            }
        }
    } else if (n0 < 2048) {
        #pragma unroll
        for (int mf = 0; mf < 8; mf++) {
            int row = rowb + mf * 16;
            #pragma unroll
            for (int nf = 0; nf < 4; nf++) {
                int col = colb + nf * 16;
                float bv = bias[col];
                #pragma unroll
                for (int r = 0; r < 4; r++)
                    k_buf[(size_t)(row + r) * 1024 + (col - 1024)] =
                        f32_to_bf16(acc[mf][nf][r] + bv);
            }
        }
    } else {
        #pragma unroll
        for (int mf = 0; mf < 8; mf++) {
            int row = rowb + mf * 16;
            int bb = row >> 11, pos = row & 2047;
            #pragma unroll
            for (int nf = 0; nf < 4; nf++) {
                int col = colb + nf * 16;
                int dg = col - 2048;
                float bv = bias[col];
                unsigned long long pk =
                    pack4(acc[mf][nf][0] + bv, acc[mf][nf][1] + bv,
                          acc[mf][nf][2] + bv, acc[mf][nf][3] + bv);
                *(unsigned long long*)(vT +
                    ((size_t)((bb * 16 + (dg >> 6)) * 64 + (dg & 63))) * 2048 + pos) = pk;
            }
        }
    }
}

// ---------------- GEMM (128x128) for out-proj ----------------

__global__ __launch_bounds__(256) void gemm_bf16_f32(
    const unsigned short* __restrict__ A,   // [M][K] bf16
    const unsigned short* __restrict__ Bt,  // [N][K] bf16
    const float* __restrict__ bias,         // [N] f32
    float* __restrict__ C, int M, int N, int K) {
    __shared__ __align__(16) unsigned short As[2][128][32];
    __shared__ __align__(16) unsigned short Bs[2][128][32];

    const int tid = threadIdx.x;
    const int m0 = blockIdx.y * 128;
    const int n0 = blockIdx.x * 128;
    const int lane = tid & 63, w4 = tid >> 6;
    const int wr = w4 >> 1, wc = w4 & 1;
    const int lq = lane & 15, lk = lane >> 4;

    const int srow = lane >> 2;
    const int sk = (lane & 3) * 8;
    const unsigned short* ap = A  + (size_t)(m0 + w4 * 16 + srow) * K + sk;
    const unsigned short* bp = Bt + (size_t)(n0 + w4 * 16 + srow) * K + sk;

    f32x4 acc[4][4];
    #pragma unroll
    for (int m = 0; m < 4; m++)
        #pragma unroll
        for (int n = 0; n < 4; n++)
            #pragma unroll
            for (int r = 0; r < 4; r++) acc[m][n][r] = 0.f;

    gload16(ap,                  &As[0][w4 * 16][0]);
    gload16(ap + (size_t)64 * K, &As[0][64 + w4 * 16][0]);
    gload16(bp,                  &Bs[0][w4 * 16][0]);
    gload16(bp + (size_t)64 * K, &Bs[0][64 + w4 * 16][0]);
    __syncthreads();

    int buf = 0;
    for (int k0 = 0; k0 < K; k0 += 32) {
        if (k0 + 32 < K) {
            const unsigned short* ap2 = ap + k0 + 32;
            const unsigned short* bp2 = bp + k0 + 32;
            gload16(ap2,                  &As[buf ^ 1][w4 * 16][0]);
            gload16(ap2 + (size_t)64 * K, &As[buf ^ 1][64 + w4 * 16][0]);
            gload16(bp2,                  &Bs[buf ^ 1][w4 * 16][0]);
            gload16(bp2 + (size_t)64 * K, &Bs[buf ^ 1][64 + w4 * 16][0]);
        }
        s16x8 af[4], bfr[4];
        #pragma unroll
        for (int m = 0; m < 4; m++)
            af[m] = *(const s16x8*)(&As[buf][wr * 64 + m * 16 + lq][lk * 8]);
        #pragma unroll
        for (int n = 0; n < 4; n++)
            bfr[n] = *(const s16x8*)(&Bs[buf][wc * 64 + n * 16 + lq][lk * 8]);
        #pragma unroll
        for (int m = 0; m < 4; m++)
            #pragma unroll
            for (int n = 0; n < 4; n++)
                acc[m][n] = mfma_bf16(af[m], bfr[n], acc[m][n]);
        __syncthreads();
        buf ^= 1;
    }

    #pragma unroll
    for (int m = 0; m < 4; m++) {
        int row = m0 + wr * 64 + m * 16 + lk * 4;
        #pragma unroll
        for (int n = 0; n < 4; n++) {
            int col = n0 + wc * 64 + n * 16 + lq;
            float bv = bias[col];
            #pragma unroll
            for (int r = 0; r < 4; r++)
                C[(size_t)(row + r) * N + col] = acc[m][n][r] + bv;
        }
    }
}

// ---------------- flash attention: sequentially-paired q-tiles --------------
// grid: 1024 1D blocks; bid = pj*64 + bh (bid%8 = bh%8 -> per-bh XCD locality).
// Block pj runs q-tile 31-pj (32-pj kv-tiles) THEN q-tile pj (pj+1 kv-tiles):
// uniform 33 units per block, one stream's registers live at a time (no spill).
// Per-stream body identical to the round-5 kernel (133 us, 68 VGPR).

__global__ __launch_bounds__(256) void attn_kernel(
    const unsigned short* __restrict__ q_buf,
    const unsigned short* __restrict__ k_buf,
    const unsigned short* __restrict__ vT,
    unsigned short* __restrict__ out) {
    __shared__ __align__(16) char lds[24576];
    char* Ks = lds;
    char* Vs = lds + 8192;

    const int bid = blockIdx.x;
    const int bh = bid & 63;
    const int pj = bid >> 6;               // 0..15
    const int b = bh >> 4, h = bh & 15;
    const int tid = threadIdx.x, lane = tid & 63, w = tid >> 6;
    const int lq = lane & 15, lk = lane >> 4;
    char* Pw = lds + 16384 + w * 2048;

    const int srow = tid >> 3, sch = tid & 7;
    const int sby0 = (srow * 128 + sch * 16) ^ ((srow & 7) << 4);
    const int sby1 = ((srow + 32) * 128 + sch * 16) ^ ((srow & 7) << 4);
    const int swzA = (lq & 7) << 4;

    const unsigned short* kbase =
        k_buf + (size_t)b * LSEQ * 1024 + h * 64 + (size_t)srow * 1024 + sch * 8;
    const unsigned short* vbase =
        vT + (size_t)bh * 64 * 2048 + (size_t)srow * 2048 + sch * 8;

    auto run_stream = [&](int qtile, int nkv) {
        const int q_g = qtile * 64 + w * 16 + lq;
        const unsigned short* qp = q_buf + ((size_t)b * LSEQ + q_g) * 1024 + h * 64;
        const s16x8 qf0 = *(const s16x8*)(qp + lk * 8);
        const s16x8 qf1 = *(const s16x8*)(qp + 32 + lk * 8);

        const unsigned short* kp = kbase;
        const unsigned short* vp = vbase;

        float m_r = -1e30f, l_r = 0.f;
        f32x4 o[4];
        #pragma unroll
        for (int n = 0; n < 4; n++)
            #pragma unroll
            for (int r = 0; r < 4; r++) o[n][r] = 0.f;

        i32x4 r0 = *(const i32x4*)kp;
        i32x4 r1 = *(const i32x4*)(kp + (size_t)32 * 1024);
        i32x4 r2 = *(const i32x4*)vp;
        i32x4 r3 = *(const i32x4*)(vp + (size_t)32 * 2048);

        for (int kvb = 0; kvb < nkv; kvb++) {
            *(i32x4*)(Ks + sby0) = r0;
            *(i32x4*)(Ks + sby1) = r1;
            *(i32x4*)(Vs + sby0) = r2;
            *(i32x4*)(Vs + sby1) = r3;
            __syncthreads();
            if (kvb + 1 < nkv) {   // T14 prefetch: hides under compute
                kp += 64 * 1024;
                vp += 64;
                r0 = *(const i32x4*)kp;
                r1 = *(const i32x4*)(kp + (size_t)32 * 1024);
                r2 = *(const i32x4*)vp;
                r3 = *(const i32x4*)(vp + (size_t)32 * 2048);
            }

            f32x4 sT[4];
            #pragma unroll
            for (int n = 0; n < 4; n++)
                #pragma unroll
                for (int r = 0; r < 4; r++) sT[n][r] = 0.f;
            __builtin_amdgcn_s_setprio(1);
            #pragma unroll
            for (int n = 0; n < 4; n++) {
                const int rb = (n * 16 + lq) * 128;
                s16x8 a0 = *(const s16x8*)(Ks + ((rb + lk * 16) ^ swzA));
                s16x8 a1 = *(const s16x8*)(Ks + ((rb + 64 + lk * 16) ^ swzA));
                sT[n] = mfma_bf16(a0, qf0, sT[n]);
                sT[n] = mfma_bf16(a1, qf1, sT[n]);
            }
            __builtin_amdgcn_s_setprio(0);
            if (kvb == nkv - 1) {   // only the diagonal tile needs masking
                const int kv0 = kvb * 64;
                #pragma unroll
                for (int n = 0; n < 4; n++)
                    #pragma unroll
                    for (int r = 0; r < 4; r++)
                        if (kv0 + n * 16 + lk * 4 + r > q_g) sT[n][r] = -1e30f;
            }

            float mx = sT[0][0];
            #pragma unroll
            for (int n = 0; n < 4; n++)
                #pragma unroll
                for (int r = 0; r < 4; r++) mx = fmaxf(mx, sT[n][r]);
            mx = fmaxf(mx, __shfl_xor(mx, 16, 64));
            mx = fmaxf(mx, __shfl_xor(mx, 32, 64));
            if (!__all(mx <= m_r + 8.f)) {   // T13 defer-max
                const float mnew = fmaxf(m_r, mx);
                const float corr = __builtin_amdgcn_exp2f(m_r - mnew);
                m_r = mnew;
                l_r *= corr;
                #pragma unroll
                for (int n = 0; n < 4; n++)
                    #pragma unroll
                    for (int r = 0; r < 4; r++) o[n][r] *= corr;
            }
            float sum = 0.f;
            unsigned long long pk[4];
            #pragma unroll
            for (int n = 0; n < 4; n++) {
                float p0 = __builtin_amdgcn_exp2f(sT[n][0] - m_r);
                float p1 = __builtin_amdgcn_exp2f(sT[n][1] - m_r);
                float p2 = __builtin_amdgcn_exp2f(sT[n][2] - m_r);
                float p3 = __builtin_amdgcn_exp2f(sT[n][3] - m_r);
                sum += (p0 + p1) + (p2 + p3);
                pk[n] = pack4(p0, p1, p2, p3);
            }
            l_r += sum;

            #pragma unroll
            for (int n = 0; n < 4; n++)
                *(unsigned long long*)(Pw + ((lq * 128 + n * 32 + lk * 8) ^ swzA)) = pk[n];
            asm volatile("s_waitcnt lgkmcnt(0)" ::: "memory");

            __builtin_amdgcn_s_setprio(1);
            #pragma unroll
            for (int kk = 0; kk < 2; kk++) {
                s16x8 pb = *(const s16x8*)(Pw + ((lq * 128 + kk * 64 + lk * 16) ^ swzA));
                #pragma unroll
                for (int n = 0; n < 4; n++) {
                    s16x8 vf = *(const s16x8*)(Vs +
                        (((n * 16 + lq) * 128 + kk * 64 + lk * 16) ^ swzA));
                    o[n] = mfma_bf16(vf, pb, o[n]);
                }
            }
            __builtin_amdgcn_s_setprio(0);
            // raw barrier: LDS reads already consumed; prefetch stays in flight
            asm volatile("s_barrier" ::: "memory");
        }

        l_r += __shfl_xor(l_r, 16, 64);
        l_r += __shfl_xor(l_r, 32, 64);
        const float inv = 1.f / l_r;
        unsigned short* op = out + ((size_t)b * LSEQ + q_g) * 1024 + h * 64;
        #pragma unroll
        for (int n = 0; n < 4; n++) {
            *(unsigned long long*)(op + n * 16 + lk * 4) =
                pack4(o[n][0] * inv, o[n][1] * inv, o[n][2] * inv, o[n][3] * inv);
        }
    };

    run_stream(31 - pj, 32 - pj);   // long stream first
    run_stream(pj, pj + 1);         // short stream second
}

// ---------------- launch ----------------

extern "C" void kernel_launch(void* const* d_in, const int* in_sizes, int n_in,
                              void* d_out, int out_size, void* d_ws, size_t ws_size,
                              hipStream_t stream) {
    const float* x     = (const float*)d_in[0];
    const float* W_qkv = (const float*)d_in[1];
    const float* b_qkv = (const float*)d_in[2];
    const float* W_out = (const float*)d_in[3];
    const float* b_out = (const float*)d_in[4];
    float* out = (float*)d_out;

    char* p = (char*)d_ws;
    unsigned short* x_bf   = (unsigned short*)p; p += (size_t)NROWS * D_MODEL * 2;
    unsigned short* wqkv_t = (unsigned short*)p; p += (size_t)3 * D_MODEL * D_MODEL * 2;
    unsigned short* wout_t = (unsigned short*)p; p += (size_t)D_MODEL * D_MODEL * 2;
    unsigned short* q_buf  = (unsigned short*)p; p += (size_t)NROWS * D_MODEL * 2;
    unsigned short* k_buf  = (unsigned short*)p; p += (size_t)NROWS * D_MODEL * 2;
    unsigned short* vT     = (unsigned short*)p; p += (size_t)NROWS * D_MODEL * 2;
    unsigned short* attn   = (unsigned short*)p;

    hipFuncSetAttribute((const void*)gemm256_qkv,
                        hipFuncAttributeMaxDynamicSharedMemorySize, 131072);

    int n4 = NROWS * D_MODEL / 4;
    hipLaunchKernelGGL(cvt_f32_bf16, dim3((n4 + 255) / 256), dim3(256), 0, stream,
                       x, x_bf, n4);
    hipLaunchKernelGGL(transpose_cvt, dim3(3 * D_MODEL / 32, D_MODEL / 32), dim3(256),
                       0, stream, W_qkv, wqkv_t, D_MODEL, 3 * D_MODEL);
    hipLaunchKernelGGL(transpose_cvt, dim3(D_MODEL / 32, D_MODEL / 32), dim3(256),
                       0, stream, W_out, wout_t, D_MODEL, D_MODEL);
    hipLaunchKernelGGL(gemm256_qkv, dim3(3 * D_MODEL / 256, NROWS / 256),
                       dim3(512), 131072, stream, x_bf, wqkv_t, b_qkv,
                       q_buf, k_buf, vT);
    hipLaunchKernelGGL(attn_kernel, dim3(16 * 64), dim3(256), 0, stream,
                       q_buf, k_buf, vT, attn);
    hipLaunchKernelGGL(gemm_bf16_f32, dim3(D_MODEL / 128, NROWS / 128),
                       dim3(256), 0, stream, attn, wout_t, b_out, out,
                       NROWS, D_MODEL, D_MODEL);
}

// Round 8
// 264.875 us; speedup vs baseline: 1.5758x; 1.0291x over previous
//
#include <hip/hip_runtime.h>
#include <hip/hip_bf16.h>
#include <stdint.h>

#define D_MODEL 1024
#define NH 16
#define HD 64
#define LSEQ 2048
#define BATCH 4
#define NROWS (BATCH * LSEQ) /* 8192 */
#define SCALE_L2E 0.18033688011112042f /* 0.125 * log2(e) */

typedef __attribute__((ext_vector_type(8))) short s16x8;
typedef __attribute__((ext_vector_type(4))) float f32x4;
typedef __attribute__((ext_vector_type(4))) int   i32x4;

static __device__ __forceinline__ f32x4 mfma_bf16(s16x8 a, s16x8 b, f32x4 c) {
    return __builtin_amdgcn_mfma_f32_16x16x32_bf16(a, b, c, 0, 0, 0);
}

static __device__ __forceinline__ unsigned short f32_to_bf16(float f) {
    unsigned int u = __float_as_uint(f);
    u = (u + 0x7fffu + ((u >> 16) & 1u)) >> 16;
    return (unsigned short)u;
}

// packed f32x2 -> bf16x2 (T12; lo -> bits[15:0], hi -> bits[31:16])
static __device__ __forceinline__ unsigned int cvtpk(float lo, float hi) {
    unsigned int r;
    asm("v_cvt_pk_bf16_f32 %0, %1, %2" : "=v"(r) : "v"(lo), "v"(hi));
    return r;
}

// store 4 f32 as 4 bf16 (8B) without u64 shift/or chains
static __device__ __forceinline__ void store_bf16x4(void* p, float a, float b,
                                                    float c, float d) {
    uint2 t;
    t.x = cvtpk(a, b);
    t.y = cvtpk(c, d);
    *(uint2*)p = t;
}

static __device__ __forceinline__ void gload16(const void* g, void* l) {
    __builtin_amdgcn_global_load_lds(
        (const __attribute__((address_space(1))) void*)g,
        (__attribute__((address_space(3))) void*)l, 16, 0, 0);
}

// ---------------- fused prep kernel ----------------
// blocks [0,3072): W_qkv transpose tiles (96 n-tiles x 32 k-tiles)
// blocks [3072,4096): W_out transpose tiles (32 x 32)
// blocks [4096,6144): grid-stride f32->bf16 convert of x

static __device__ __forceinline__ void transpose_tile(
    const float* __restrict__ in, unsigned short* __restrict__ out,
    int K, int N, int n0, int k0, float (*tile)[33]) {
    int tx = threadIdx.x & 31, ty = threadIdx.x >> 5; // 32 x 8
    #pragma unroll
    for (int i = 0; i < 4; i++) {
        int k = ty + i * 8;
        tile[k][tx] = in[(size_t)(k0 + k) * N + (n0 + tx)];
    }
    __syncthreads();
    #pragma unroll
    for (int i = 0; i < 4; i++) {
        int n = ty + i * 8;
        out[(size_t)(n0 + n) * K + (k0 + tx)] = f32_to_bf16(tile[tx][n]);
    }
}

__global__ __launch_bounds__(256) void prep_kernel(
    const float* __restrict__ x, const float* __restrict__ W_qkv,
    const float* __restrict__ W_out,
    unsigned short* __restrict__ x_bf, unsigned short* __restrict__ wqkv_t,
    unsigned short* __restrict__ wout_t) {
    __shared__ float tile[32][33];
    const int bid = blockIdx.x;
    if (bid < 3072) {
        transpose_tile(W_qkv, wqkv_t, 1024, 3072, (bid % 96) * 32,
                       (bid / 96) * 32, tile);
    } else if (bid < 4096) {
        int t = bid - 3072;
        transpose_tile(W_out, wout_t, 1024, 1024, (t % 32) * 32,
                       (t / 32) * 32, tile);
    } else {
        const int t = bid - 4096;                 // 2048 cvt blocks
        const int n4 = NROWS * D_MODEL / 4;       // 2097152
        for (int i = t * 256 + (int)threadIdx.x; i < n4; i += 2048 * 256) {
            float4 v = ((const float4*)x)[i];
            ushort4 o;
            o.x = f32_to_bf16(v.x); o.y = f32_to_bf16(v.y);
            o.z = f32_to_bf16(v.z); o.w = f32_to_bf16(v.w);
            ((ushort4*)x_bf)[i] = o;
        }
    }
}

// ============ 256x256 8-phase QKV GEMM (T1+T2+T3+T4+T5) ============

__global__ __launch_bounds__(512, 2) void gemm256_qkv(
    const unsigned short* __restrict__ A,    // [8192][1024]
    const unsigned short* __restrict__ Bt,   // [3072][1024]
    const float* __restrict__ bias,          // [3072]
    unsigned short* __restrict__ q_buf, unsigned short* __restrict__ k_buf,
    unsigned short* __restrict__ vT) {
    extern __shared__ float4 smv[];
    char* sm = (char*)smv;
    const int K = 1024, NT = 16;
    const int tid = threadIdx.x;
    const int lane = tid & 63, w = tid >> 6;
    const int wm = w >> 2, wn = w & 3;
    const int lq = lane & 15, lk = lane >> 4;
    // T1 XCD chunked swizzle (384 % 8 == 0 -> bijective)
    int bid0 = blockIdx.y * 12 + blockIdx.x;
    bid0 = (bid0 & 7) * 48 + (bid0 >> 3);
    const int m0 = (bid0 / 12) * 256, n0 = (bid0 % 12) * 256;

    const unsigned short* GA = A + (size_t)m0 * K;
    const unsigned short* GB = Bt + (size_t)n0 * K;

    auto stage = [&](const unsigned short* G, int mat, int t, int half) {
        char* base = sm + (t & 1) * 65536 + mat * 32768 + half * 16384;
        const unsigned short* g0 = G + (size_t)(half * 128) * K + t * 64;
        #pragma unroll
        for (int j = 0; j < 2; j++) {
            int c = j * 512 + tid;
            int row = c >> 3, cc = c & 7;
            int cg = cc ^ (row & 7);                       // inverse swizzle on src
            gload16(g0 + (size_t)row * K + cg * 8,
                    base + (j * 512 + w * 64) * 16);        // wave-uniform dest
        }
    };
    auto lda = [&](int buf, int mf, int ks) -> s16x8 {
        int byte = (((mf * 16 + lq) * 128 + ks * 64 + lk * 16)) ^ ((lq & 7) << 4);
        return *(const s16x8*)(sm + buf * 65536 + wm * 16384 + byte);
    };
    auto ldb = [&](int buf, int nf, int ks) -> s16x8 {
        int byte = ((((wn & 1) * 64 + nf * 16 + lq) * 128 + ks * 64 + lk * 16)) ^
                   ((lq & 7) << 4);
        return *(const s16x8*)(sm + buf * 65536 + 32768 + (wn >> 1) * 16384 + byte);
    };

    f32x4 acc[8][4];
    #pragma unroll
    for (int m = 0; m < 8; m++)
        #pragma unroll
        for (int n = 0; n < 4; n++)
            #pragma unroll
            for (int r = 0; r < 4; r++) acc[m][n][r] = 0.f;

    stage(GA, 0, 0, 0); stage(GA, 0, 0, 1); stage(GB, 1, 0, 0); stage(GB, 1, 0, 1);
    stage(GA, 0, 1, 0); stage(GA, 0, 1, 1); stage(GB, 1, 1, 0);
    asm volatile("s_waitcnt vmcnt(6)" ::: "memory");
    __builtin_amdgcn_s_barrier();

    s16x8 alo[4][2], ahi[4][2], blo[2][2], bhi[2][2];
    for (int t = 0; t < NT; t++) {
        const int buf = t & 1;
        #pragma unroll
        for (int mf = 0; mf < 4; mf++)
            #pragma unroll
            for (int ks = 0; ks < 2; ks++) alo[mf][ks] = lda(buf, mf, ks);
        #pragma unroll
        for (int nf = 0; nf < 2; nf++)
            #pragma unroll
            for (int ks = 0; ks < 2; ks++) blo[nf][ks] = ldb(buf, nf, ks);
        if (t + 1 < NT) stage(GB, 1, t + 1, 1);
        __builtin_amdgcn_s_barrier();
        asm volatile("s_waitcnt lgkmcnt(0)" ::: "memory");
        __builtin_amdgcn_s_setprio(1);
        #pragma unroll
        for (int mf = 0; mf < 4; mf++)
            #pragma unroll
            for (int nf = 0; nf < 2; nf++)
                #pragma unroll
                for (int ks = 0; ks < 2; ks++)
                    acc[mf][nf] = mfma_bf16(alo[mf][ks], blo[nf][ks], acc[mf][nf]);
        __builtin_amdgcn_s_setprio(0);
        __builtin_amdgcn_s_barrier();
        #pragma unroll
        for (int nf = 0; nf < 2; nf++)
            #pragma unroll
            for (int ks = 0; ks < 2; ks++) bhi[nf][ks] = ldb(buf, 2 + nf, ks);
        __builtin_amdgcn_s_barrier();
        asm volatile("s_waitcnt lgkmcnt(0)" ::: "memory");
        __builtin_amdgcn_s_setprio(1);
        #pragma unroll
        for (int mf = 0; mf < 4; mf++)
            #pragma unroll
            for (int nf = 0; nf < 2; nf++)
                #pragma unroll
                for (int ks = 0; ks < 2; ks++)
                    acc[mf][2 + nf] = mfma_bf16(alo[mf][ks], bhi[nf][ks], acc[mf][2 + nf]);
        __builtin_amdgcn_s_setprio(0);
        __builtin_amdgcn_s_barrier();
        #pragma unroll
        for (int mf = 0; mf < 4; mf++)
            #pragma unroll
            for (int ks = 0; ks < 2; ks++) ahi[mf][ks] = lda(buf, 4 + mf, ks);
        if (t + 2 < NT) stage(GB, 1, t + 2, 0);
        __builtin_amdgcn_s_barrier();
        asm volatile("s_waitcnt lgkmcnt(0)" ::: "memory");
        __builtin_amdgcn_s_setprio(1);
        #pragma unroll
        for (int mf = 0; mf < 4; mf++)
            #pragma unroll
            for (int nf = 0; nf < 2; nf++)
                #pragma unroll
                for (int ks = 0; ks < 2; ks++)
                    acc[4 + mf][nf] = mfma_bf16(ahi[mf][ks], blo[nf][ks], acc[4 + mf][nf]);
        __builtin_amdgcn_s_setprio(0);
        __builtin_amdgcn_s_barrier();
        if (t + 2 < NT) { stage(GA, 0, t + 2, 0); stage(GA, 0, t + 2, 1); }
        __builtin_amdgcn_s_barrier();
        asm volatile("s_waitcnt lgkmcnt(0)" ::: "memory");
        __builtin_amdgcn_s_setprio(1);
        #pragma unroll
        for (int mf = 0; mf < 4; mf++)
            #pragma unroll
            for (int nf = 0; nf < 2; nf++)
                #pragma unroll
                for (int ks = 0; ks < 2; ks++)
                    acc[4 + mf][2 + nf] = mfma_bf16(ahi[mf][ks], bhi[nf][ks], acc[4 + mf][2 + nf]);
        __builtin_amdgcn_s_setprio(0);
        if (t + 2 < NT) {
            asm volatile("s_waitcnt vmcnt(6)" ::: "memory");
        } else if (t + 1 < NT) {
            asm volatile("s_waitcnt vmcnt(0)" ::: "memory");
        }
        __builtin_amdgcn_s_barrier();
    }

    const int rowb = m0 + wm * 128 + lk * 4;
    const int colb = n0 + wn * 64 + lq;
    if (n0 < 1024) {
        #pragma unroll
        for (int mf = 0; mf < 8; mf++) {
            int row = rowb + mf * 16;
            #pragma unroll
            for (int nf = 0; nf < 4; nf++) {
                int col = colb + nf * 16;
                float bv = bias[col];
                #pragma unroll
                for (int r = 0; r < 4; r++)
                    q_buf[(size_t)(row + r) * 1024 + col] =
                        f32_to_bf16((acc[mf][nf][r] + bv) * SCALE_L2E);
            }
        }
    } else if (n0 < 2048) {
        #pragma unroll
        for (int mf = 0; mf < 8; mf++) {
            int row = rowb + mf * 16;
            #pragma unroll
            for (int nf = 0; nf < 4; nf++) {
                int col = colb + nf * 16;
                float bv = bias[col];
                #pragma unroll
                for (int r = 0; r < 4; r++)
                    k_buf[(size_t)(row + r) * 1024 + (col - 1024)] =
                        f32_to_bf16(acc[mf][nf][r] + bv);
            }
        }
    } else {
        #pragma unroll
        for (int mf = 0; mf < 8; mf++) {
            int row = rowb + mf * 16;
            int bb = row >> 11, pos = row & 2047;
            #pragma unroll
            for (int nf = 0; nf < 4; nf++) {
                int col = colb + nf * 16;
                int dg = col - 2048;
                float bv = bias[col];
                store_bf16x4(vT +
                    ((size_t)((bb * 16 + (dg >> 6)) * 64 + (dg & 63))) * 2048 + pos,
                    acc[mf][nf][0] + bv, acc[mf][nf][1] + bv,
                    acc[mf][nf][2] + bv, acc[mf][nf][3] + bv);
            }
        }
    }
}

// ---------------- GEMM (128x128) for out-proj ----------------

__global__ __launch_bounds__(256) void gemm_bf16_f32(
    const unsigned short* __restrict__ A,   // [M][K] bf16
    const unsigned short* __restrict__ Bt,  // [N][K] bf16
    const float* __restrict__ bias,         // [N] f32
    float* __restrict__ C, int M, int N, int K) {
    __shared__ __align__(16) unsigned short As[2][128][32];
    __shared__ __align__(16) unsigned short Bs[2][128][32];

    const int tid = threadIdx.x;
    // T1 XCD chunked swizzle (grid 8x64 = 512, 512 % 8 == 0)
    int bid0 = blockIdx.y * 8 + blockIdx.x;
    bid0 = (bid0 & 7) * 64 + (bid0 >> 3);
    const int m0 = (bid0 >> 3) * 128;
    const int n0 = (bid0 & 7) * 128;
    const int lane = tid & 63, w4 = tid >> 6;
    const int wr = w4 >> 1, wc = w4 & 1;
    const int lq = lane & 15, lk = lane >> 4;

    const int srow = lane >> 2;
    const int sk = (lane & 3) * 8;
    const unsigned short* ap = A  + (size_t)(m0 + w4 * 16 + srow) * K + sk;
    const unsigned short* bp = Bt + (size_t)(n0 + w4 * 16 + srow) * K + sk;

    f32x4 acc[4][4];
    #pragma unroll
    for (int m = 0; m < 4; m++)
        #pragma unroll
        for (int n = 0; n < 4; n++)
            #pragma unroll
            for (int r = 0; r < 4; r++) acc[m][n][r] = 0.f;

    gload16(ap,                  &As[0][w4 * 16][0]);
    gload16(ap + (size_t)64 * K, &As[0][64 + w4 * 16][0]);
    gload16(bp,                  &Bs[0][w4 * 16][0]);
    gload16(bp + (size_t)64 * K, &Bs[0][64 + w4 * 16][0]);
    __syncthreads();

    int buf = 0;
    for (int k0 = 0; k0 < K; k0 += 32) {
        if (k0 + 32 < K) {
            const unsigned short* ap2 = ap + k0 + 32;
            const unsigned short* bp2 = bp + k0 + 32;
            gload16(ap2,                  &As[buf ^ 1][w4 * 16][0]);
            gload16(ap2 + (size_t)64 * K, &As[buf ^ 1][64 + w4 * 16][0]);
            gload16(bp2,                  &Bs[buf ^ 1][w4 * 16][0]);
            gload16(bp2 + (size_t)64 * K, &Bs[buf ^ 1][64 + w4 * 16][0]);
        }
        s16x8 af[4], bfr[4];
        #pragma unroll
        for (int m = 0; m < 4; m++)
            af[m] = *(const s16x8*)(&As[buf][wr * 64 + m * 16 + lq][lk * 8]);
        #pragma unroll
        for (int n = 0; n < 4; n++)
            bfr[n] = *(const s16x8*)(&Bs[buf][wc * 64 + n * 16 + lq][lk * 8]);
        #pragma unroll
        for (int m = 0; m < 4; m++)
            #pragma unroll
            for (int n = 0; n < 4; n++)
                acc[m][n] = mfma_bf16(af[m], bfr[n], acc[m][n]);
        __syncthreads();
        buf ^= 1;
    }

    #pragma unroll
    for (int m = 0; m < 4; m++) {
        int row = m0 + wr * 64 + m * 16 + lk * 4;
        #pragma unroll
        for (int n = 0; n < 4; n++) {
            int col = n0 + wc * 64 + n * 16 + lq;
            float bv = bias[col];
            #pragma unroll
            for (int r = 0; r < 4; r++)
                C[(size_t)(row + r) * N + col] = acc[m][n][r] + bv;
        }
    }
}

// ---------------- flash attention: sequentially-paired q-tiles --------------
// grid: 1024 1D blocks; bid = pj*64 + bh (bid%8 = bh%8 -> per-bh XCD locality).
// Block pj runs q-tile 31-pj (32-pj kv-tiles) THEN q-tile pj (pj+1 kv-tiles).

__global__ __launch_bounds__(256) void attn_kernel(
    const unsigned short* __restrict__ q_buf,
    const unsigned short* __restrict__ k_buf,
    const unsigned short* __restrict__ vT,
    unsigned short* __restrict__ out) {
    __shared__ __align__(16) char lds[24576];
    char* Ks = lds;
    char* Vs = lds + 8192;

    const int bid = blockIdx.x;
    const int bh = bid & 63;
    const int pj = bid >> 6;               // 0..15
    const int b = bh >> 4, h = bh & 15;
    const int tid = threadIdx.x, lane = tid & 63, w = tid >> 6;
    const int lq = lane & 15, lk = lane >> 4;
    char* Pw = lds + 16384 + w * 2048;

    const int srow = tid >> 3, sch = tid & 7;
    const int sby0 = (srow * 128 + sch * 16) ^ ((srow & 7) << 4);
    const int sby1 = ((srow + 32) * 128 + sch * 16) ^ ((srow & 7) << 4);
    const int swzA = (lq & 7) << 4;

    const unsigned short* kbase =
        k_buf + (size_t)b * LSEQ * 1024 + h * 64 + (size_t)srow * 1024 + sch * 8;
    const unsigned short* vbase =
        vT + (size_t)bh * 64 * 2048 + (size_t)srow * 2048 + sch * 8;

    auto run_stream = [&](int qtile, int nkv) {
        const int q_g = qtile * 64 + w * 16 + lq;
        const unsigned short* qp = q_buf + ((size_t)b * LSEQ + q_g) * 1024 + h * 64;
        const s16x8 qf0 = *(const s16x8*)(qp + lk * 8);
        const s16x8 qf1 = *(const s16x8*)(qp + 32 + lk * 8);

        const unsigned short* kp = kbase;
        const unsigned short* vp = vbase;

        float m_r = -1e30f, l_r = 0.f;
        f32x4 o[4];
        #pragma unroll
        for (int n = 0; n < 4; n++)
            #pragma unroll
            for (int r = 0; r < 4; r++) o[n][r] = 0.f;

        i32x4 r0 = *(const i32x4*)kp;
        i32x4 r1 = *(const i32x4*)(kp + (size_t)32 * 1024);
        i32x4 r2 = *(const i32x4*)vp;
        i32x4 r3 = *(const i32x4*)(vp + (size_t)32 * 2048);

        for (int kvb = 0; kvb < nkv; kvb++) {
            *(i32x4*)(Ks + sby0) = r0;
            *(i32x4*)(Ks + sby1) = r1;
            *(i32x4*)(Vs + sby0) = r2;
            *(i32x4*)(Vs + sby1) = r3;
            __syncthreads();
            if (kvb + 1 < nkv) {   // T14 prefetch: hides under compute
                kp += 64 * 1024;
                vp += 64;
                r0 = *(const i32x4*)kp;
                r1 = *(const i32x4*)(kp + (size_t)32 * 1024);
                r2 = *(const i32x4*)vp;
                r3 = *(const i32x4*)(vp + (size_t)32 * 2048);
            }

            f32x4 sT[4];
            #pragma unroll
            for (int n = 0; n < 4; n++)
                #pragma unroll
                for (int r = 0; r < 4; r++) sT[n][r] = 0.f;
            __builtin_amdgcn_s_setprio(1);
            #pragma unroll
            for (int n = 0; n < 4; n++) {
                const int rb = (n * 16 + lq) * 128;
                s16x8 a0 = *(const s16x8*)(Ks + ((rb + lk * 16) ^ swzA));
                s16x8 a1 = *(const s16x8*)(Ks + ((rb + 64 + lk * 16) ^ swzA));
                sT[n] = mfma_bf16(a0, qf0, sT[n]);
                sT[n] = mfma_bf16(a1, qf1, sT[n]);
            }
            __builtin_amdgcn_s_setprio(0);
            if (kvb == nkv - 1) {   // only the diagonal tile needs masking
                const int kv0 = kvb * 64;
                #pragma unroll
                for (int n = 0; n < 4; n++)
                    #pragma unroll
                    for (int r = 0; r < 4; r++)
                        if (kv0 + n * 16 + lk * 4 + r > q_g) sT[n][r] = -1e30f;
            }

            // T17 max3 tree (short dep chain; clang fuses nested fmaxf)
            float a0 = fmaxf(fmaxf(sT[0][0], sT[0][1]), sT[0][2]);
            float a1 = fmaxf(fmaxf(sT[0][3], sT[1][0]), sT[1][1]);
            float a2 = fmaxf(fmaxf(sT[1][2], sT[1][3]), sT[2][0]);
            float a3 = fmaxf(fmaxf(sT[2][1], sT[2][2]), sT[2][3]);
            float a4 = fmaxf(fmaxf(sT[3][0], sT[3][1]), sT[3][2]);
            float mx = fmaxf(fmaxf(fmaxf(a0, a1), a2),
                             fmaxf(fmaxf(a3, a4), sT[3][3]));
            mx = fmaxf(mx, __shfl_xor(mx, 16, 64));
            mx = fmaxf(mx, __shfl_xor(mx, 32, 64));
            if (!__all(mx <= m_r + 8.f)) {   // T13 defer-max
                const float mnew = fmaxf(m_r, mx);
                const float corr = __builtin_amdgcn_exp2f(m_r - mnew);
                m_r = mnew;
                l_r *= corr;
                #pragma unroll
                for (int n = 0; n < 4; n++)
                    #pragma unroll
                    for (int r = 0; r < 4; r++) o[n][r] *= corr;
            }
            float sum = 0.f;
            uint2 pk[4];
            #pragma unroll
            for (int n = 0; n < 4; n++) {
                float p0 = __builtin_amdgcn_exp2f(sT[n][0] - m_r);
                float p1 = __builtin_amdgcn_exp2f(sT[n][1] - m_r);
                float p2 = __builtin_amdgcn_exp2f(sT[n][2] - m_r);
                float p3 = __builtin_amdgcn_exp2f(sT[n][3] - m_r);
                sum += (p0 + p1) + (p2 + p3);
                pk[n].x = cvtpk(p0, p1);
                pk[n].y = cvtpk(p2, p3);
            }
            l_r += sum;

            #pragma unroll
            for (int n = 0; n < 4; n++)
                *(uint2*)(Pw + ((lq * 128 + n * 32 + lk * 8) ^ swzA)) = pk[n];
            asm volatile("s_waitcnt lgkmcnt(0)" ::: "memory");

            __builtin_amdgcn_s_setprio(1);
            #pragma unroll
            for (int kk = 0; kk < 2; kk++) {
                s16x8 pb = *(const s16x8*)(Pw + ((lq * 128 + kk * 64 + lk * 16) ^ swzA));
                #pragma unroll
                for (int n = 0; n < 4; n++) {
                    s16x8 vf = *(const s16x8*)(Vs +
                        (((n * 16 + lq) * 128 + kk * 64 + lk * 16) ^ swzA));
                    o[n] = mfma_bf16(vf, pb, o[n]);
                }
            }
            __builtin_amdgcn_s_setprio(0);
            // raw barrier: LDS reads already consumed; prefetch stays in flight
            asm volatile("s_barrier" ::: "memory");
        }

        l_r += __shfl_xor(l_r, 16, 64);
        l_r += __shfl_xor(l_r, 32, 64);
        const float inv = 1.f / l_r;
        unsigned short* op = out + ((size_t)b * LSEQ + q_g) * 1024 + h * 64;
        #pragma unroll
        for (int n = 0; n < 4; n++)
            store_bf16x4(op + n * 16 + lk * 4, o[n][0] * inv, o[n][1] * inv,
                         o[n][2] * inv, o[n][3] * inv);
    };

    run_stream(31 - pj, 32 - pj);   // long stream first
    run_stream(pj, pj + 1);         // short stream second
}

// ---------------- launch ----------------

extern "C" void kernel_launch(void* const* d_in, const int* in_sizes, int n_in,
                              void* d_out, int out_size, void* d_ws, size_t ws_size,
                              hipStream_t stream) {
    const float* x     = (const float*)d_in[0];
    const float* W_qkv = (const float*)d_in[1];
    const float* b_qkv = (const float*)d_in[2];
    const float* W_out = (const float*)d_in[3];
    const float* b_out = (const float*)d_in[4];
    float* out = (float*)d_out;

    char* p = (char*)d_ws;
    unsigned short* x_bf   = (unsigned short*)p; p += (size_t)NROWS * D_MODEL * 2;
    unsigned short* wqkv_t = (unsigned short*)p; p += (size_t)3 * D_MODEL * D_MODEL * 2;
    unsigned short* wout_t = (unsigned short*)p; p += (size_t)D_MODEL * D_MODEL * 2;
    unsigned short* q_buf  = (unsigned short*)p; p += (size_t)NROWS * D_MODEL * 2;
    unsigned short* k_buf  = (unsigned short*)p; p += (size_t)NROWS * D_MODEL * 2;
    unsigned short* vT     = (unsigned short*)p; p += (size_t)NROWS * D_MODEL * 2;
    unsigned short* attn   = (unsigned short*)p;

    hipFuncSetAttribute((const void*)gemm256_qkv,
                        hipFuncAttributeMaxDynamicSharedMemorySize, 131072);

    hipLaunchKernelGGL(prep_kernel, dim3(6144), dim3(256), 0, stream,
                       x, W_qkv, W_out, x_bf, wqkv_t, wout_t);
    hipLaunchKernelGGL(gemm256_qkv, dim3(3 * D_MODEL / 256, NROWS / 256),
                       dim3(512), 131072, stream, x_bf, wqkv_t, b_qkv,
                       q_buf, k_buf, vT);
    hipLaunchKernelGGL(attn_kernel, dim3(16 * 64), dim3(256), 0, stream,
                       q_buf, k_buf, vT, attn);
    hipLaunchKernelGGL(gemm_bf16_f32, dim3(D_MODEL / 128, NROWS / 128),
                       dim3(256), 0, stream, attn, wout_t, b_out, out,
                       NROWS, D_MODEL, D_MODEL);
}